// Round 4
// baseline (808.351 us; speedup 1.0000x reference)
//
#include <hip/hip_runtime.h>

// ---------------------------------------------------------------------------
// GCN 2-layer forward on MI355X.
// R9: non-agg1 mass (~471us) is spread, not one pig. Common fix: kill
// barrier/latency-bound structure. GEMMs: BN == full N means A has ZERO
// cross-block reuse and B (256KB/32KB) is L2-resident -> drop LDS+barriers
// entirely; wave owns 32 rows x full N, A direct from global (fp32->bf16 in
// regs, explicit next-K prefetch), B direct from L2. gemm1 acc[2][16]
// (~190 VGPR, 2 waves/SIMD, no-barrier stream), gemm2 acc[2][4] (tiny).
// scatter: EPB 8192->2048 (391->1563 blocks), CAP_BIN 16 (mean 5.2).
// build: 512 threads (halve edge-loop trips). aggs byte-clamped: unchanged.
// Pipeline: packW+init -> scatter -> build -> GEMM1(*dinv,->q8) ->
//           agg1(+relu,bf16) -> GEMM2(*dinv,->q8) -> agg2 -> d_out(fp32)
// ---------------------------------------------------------------------------

typedef short s16x8 __attribute__((ext_vector_type(8)));   // 8 bf16 = 4 VGPRs
typedef float f32x4 __attribute__((ext_vector_type(4)));

static constexpr int IN_DIM = 512;
static constexpr int HID = 256;
static constexpr int OUTD = 64;

static constexpr int BKT_SHIFT = 8;           // 256 nodes / bucket
static constexpr int MAX_NB = 400;            // >= ceil(100000/256)=391
static constexpr int CAP_BIN = 16;            // scatter LDS bin depth
static constexpr int EDGES_PER_BLOCK = 2048;  // scatter chunk (mean bin 5.2)
static constexpr int SEG_CAP = 16384;         // bucket segment (mean 8192 +90s)

static __device__ __forceinline__ float bf2f(unsigned short u) {
  unsigned int x = ((unsigned int)u) << 16;
  float f;
  __builtin_memcpy(&f, &x, 4);
  return f;
}
static __device__ __forceinline__ unsigned short f2bf(float f) {
  unsigned int x;
  __builtin_memcpy(&x, &f, 4);
  unsigned int r = x + 0x7fffu + ((x >> 16) & 1u);  // RNE
  return (unsigned short)(r >> 16);
}
// byte k of x as float (LLVM folds to v_cvt_f32_ubyteN)
static __device__ __forceinline__ float ub(unsigned int x, int k) {
  return (float)((x >> (8 * k)) & 0xffu);
}

// ---------------- fused: pack W1/W2 to bf16 [N,K] + init bucket cursors -----
__global__ __launch_bounds__(256) void pack_init_kernel(
    const float* __restrict__ W1, const float* __restrict__ W2,
    short* __restrict__ Wt1, short* __restrict__ Wt2,
    unsigned* __restrict__ bucket_cursor) {
  int idx = blockIdx.x * blockDim.x + threadIdx.x;
  if (idx < IN_DIM * HID) {  // Wt1[n*K+k] = W1[k*N+n]
    int n = idx / IN_DIM, k = idx - n * IN_DIM;
    Wt1[idx] = (short)f2bf(W1[(size_t)k * HID + n]);
  }
  if (idx < HID * OUTD) {
    int n = idx / HID, k = idx - n * HID;
    Wt2[idx] = (short)f2bf(W2[(size_t)k * OUTD + n]);
  }
  if (idx < 512) bucket_cursor[idx] = (unsigned)idx * SEG_CAP;
}

// bin edges by dst-bucket into fixed segments; entry = (src<<8)|(dst&255)
__global__ __launch_bounds__(256) void scatter_kernel(
    const int* __restrict__ src, const int* __restrict__ dst, int E,
    unsigned* __restrict__ bucket_cursor, unsigned* __restrict__ entry_buf) {
  __shared__ unsigned cnt[MAX_NB];
  __shared__ unsigned poss[MAX_NB];
  __shared__ unsigned buf[MAX_NB * CAP_BIN];
  const int tid = threadIdx.x;
  const int e0 = blockIdx.x * EDGES_PER_BLOCK;
  const int e1 = min(E, e0 + EDGES_PER_BLOCK);
  for (int i = tid; i < MAX_NB; i += 256) cnt[i] = 0;
  __syncthreads();
  for (int e = e0 + tid; e < e1; e += 256) {
    int d = dst[e];
    unsigned entry = (((unsigned)src[e]) << 8) | ((unsigned)d & 255u);
    int bkt = d >> BKT_SHIFT;
    unsigned slot = atomicAdd(&cnt[bkt], 1u);
    if (slot < CAP_BIN) {
      buf[bkt * CAP_BIN + slot] = entry;
    } else {  // rare overflow: direct scattered write
      unsigned pos = atomicAdd(&bucket_cursor[bkt], 1u);
      entry_buf[pos] = entry;
    }
  }
  __syncthreads();
  for (int b = tid; b < MAX_NB; b += 256) {
    unsigned c = min(cnt[b], (unsigned)CAP_BIN);
    poss[b] = c ? atomicAdd(&bucket_cursor[b], c) : 0u;
  }
  __syncthreads();
  for (int b0 = 0; b0 < MAX_NB; b0 += 16) {
    int b = b0 + (tid >> 4);
    int i = tid & 15;
    unsigned c = min(cnt[b], (unsigned)CAP_BIN);
    if ((unsigned)i < c) entry_buf[poss[b] + i] = buf[b * CAP_BIN + i];
  }
}

// one block per bucket: LDS counting sort -> csr in bucket segment; emits
// dinv, row_start, row_cnt. 512 threads (edge loops); scan confined to <256.
__global__ __launch_bounds__(512) void build_kernel(
    const unsigned* __restrict__ entry_buf,
    const unsigned* __restrict__ bucket_cursor, int Nn,
    int* __restrict__ csr_src, unsigned* __restrict__ row_start,
    unsigned* __restrict__ row_cnt, float* __restrict__ dinv) {
  __shared__ unsigned hist[256];
  __shared__ unsigned scn[256];
  const int tid = threadIdx.x;
  const int b = blockIdx.x;
  const unsigned nb0 = (unsigned)b * SEG_CAP;
  const int n_e = (int)(bucket_cursor[b] - nb0);

  if (tid < 256) hist[tid] = 0;
  __syncthreads();
  for (int i = tid; i < n_e; i += 512)
    atomicAdd(&hist[entry_buf[nb0 + i] & 255u], 1u);
  __syncthreads();

  unsigned v = (tid < 256) ? hist[tid] : 0u;
  if (tid < 256) scn[tid] = v;
  __syncthreads();
  for (int off = 1; off < 256; off <<= 1) {
    unsigned t = (tid < 256 && tid >= off) ? scn[tid - off] : 0u;
    __syncthreads();
    if (tid < 256) scn[tid] += t;
    __syncthreads();
  }
  unsigned excl = 0;
  if (tid < 256) {
    excl = scn[tid] - v;
    int node = (b << BKT_SHIFT) + tid;
    if (node < Nn) {
      dinv[node] = rsqrtf((float)v + 1.0f);  // +1 self loop
      row_start[node] = nb0 + excl;
      row_cnt[node] = v;
    }
  }
  __syncthreads();
  if (tid < 256) {
    scn[tid] = excl;
    hist[tid] = 0;  // reuse as per-node rank counters
  }
  __syncthreads();

  for (int i = tid; i < n_e; i += 512) {
    unsigned en = entry_buf[nb0 + i];
    unsigned d = en & 255u;
    unsigned r = atomicAdd(&hist[d], 1u);
    csr_src[nb0 + scn[d] + r] = (int)(en >> 8);
  }
}

// ---------------- GEMM1: q1 = quant8(dinv[row] * (x @ Wt1^T)) ---------------
// No LDS, no barriers: wave owns 32 rows x full N=256 (acc[2][16]).
// A (fp32) loaded per-lane from global with next-K prefetch, cvt in regs;
// B (Wt1, 256KB) is L2-resident -- loaded per-fragment from global.
__global__ __launch_bounds__(256) void gemm1_kernel(
    const float* __restrict__ A, const short* __restrict__ Bt,
    unsigned char* __restrict__ q, float* __restrict__ qscale,
    const float* __restrict__ dinv, int M) {
  constexpr int K = IN_DIM;  // 512
  constexpr int N = HID;     // 256
  const int lane = threadIdx.x & 63;
  const int wid = blockIdx.x * 4 + (threadIdx.x >> 6);
  const int r0 = wid * 32;
  if (r0 >= M) return;
  const int lm = lane & 15, lq = lane >> 4;

  f32x4 acc[2][16];
#pragma unroll
  for (int mi = 0; mi < 2; mi++)
#pragma unroll
    for (int ni = 0; ni < 16; ni++) acc[mi][ni] = f32x4{0.f, 0.f, 0.f, 0.f};

  const float* pa0 = A + (size_t)(r0 + lm) * K + lq * 8;
  const float* pa1 = A + (size_t)(r0 + 16 + lm) * K + lq * 8;

  auto ldA = [&](const float* p, int k0) -> s16x8 {
    float4 f0 = *(const float4*)(p + k0);
    float4 f1 = *(const float4*)(p + k0 + 4);
    s16x8 v;
    v[0] = (short)f2bf(f0.x); v[1] = (short)f2bf(f0.y);
    v[2] = (short)f2bf(f0.z); v[3] = (short)f2bf(f0.w);
    v[4] = (short)f2bf(f1.x); v[5] = (short)f2bf(f1.y);
    v[6] = (short)f2bf(f1.z); v[7] = (short)f2bf(f1.w);
    return v;
  };

  s16x8 af0 = ldA(pa0, 0), af1 = ldA(pa1, 0);
  for (int k0 = 0; k0 < K; k0 += 32) {
    s16x8 nf0, nf1;
    if (k0 + 32 < K) {  // prefetch next K-step's A while MFMAs run
      nf0 = ldA(pa0, k0 + 32);
      nf1 = ldA(pa1, k0 + 32);
    }
    const short* pb = Bt + (size_t)lm * K + k0 + lq * 8;
#pragma unroll
    for (int ni = 0; ni < 16; ni++) {
      s16x8 b = *(const s16x8*)(pb + (size_t)ni * 16 * K);
      acc[0][ni] = __builtin_amdgcn_mfma_f32_16x16x32_bf16(af0, b, acc[0][ni], 0, 0, 0);
      acc[1][ni] = __builtin_amdgcn_mfma_f32_16x16x32_bf16(af1, b, acc[1][ni], 0, 0, 0);
    }
    af0 = nf0;
    af1 = nf1;
  }

  // C/D layout (m89-verified): col = lane&15, row = (lane>>4)*4 + reg
#pragma unroll
  for (int mi = 0; mi < 2; mi++)
#pragma unroll
    for (int r = 0; r < 4; r++) {
      int row = r0 + mi * 16 + lq * 4 + r;
      float di = dinv[row];
      float mx = 0.f;
#pragma unroll
      for (int ni = 0; ni < 16; ni++) mx = fmaxf(mx, fabsf(acc[mi][ni][r]));
      mx *= di;  // di >= 0
#pragma unroll
      for (int w = 1; w < 16; w <<= 1) mx = fmaxf(mx, __shfl_xor(mx, w));
      float inv = 127.0f / fmaxf(mx, 1e-30f);
#pragma unroll
      for (int ni = 0; ni < 16; ni++) {
        int qv = (int)rintf(acc[mi][ni][r] * di * inv) + 128;
        q[(size_t)row * N + ni * 16 + lm] = (unsigned char)qv;
      }
      if (lm == 0) qscale[row] = mx * (1.0f / 127.0f);
    }
}

// ---------------- GEMM2: q2 = quant8(dinv[row] * (agg1 @ Wt2^T)) ------------
// Same no-LDS form: wave owns 32 rows x full N=64 (acc[2][4], tiny VGPR).
// A is bf16 (direct 16B loads); B (Wt2, 32KB) L2-resident.
__global__ __launch_bounds__(256) void gemm2_kernel(
    const short* __restrict__ A, const short* __restrict__ Bt,
    unsigned char* __restrict__ q, float* __restrict__ qscale,
    const float* __restrict__ dinv, int M) {
  constexpr int K = HID;    // 256
  constexpr int N = OUTD;   // 64
  const int lane = threadIdx.x & 63;
  const int wid = blockIdx.x * 4 + (threadIdx.x >> 6);
  const int r0 = wid * 32;
  if (r0 >= M) return;
  const int lm = lane & 15, lq = lane >> 4;

  f32x4 acc[2][4];
#pragma unroll
  for (int mi = 0; mi < 2; mi++)
#pragma unroll
    for (int ni = 0; ni < 4; ni++) acc[mi][ni] = f32x4{0.f, 0.f, 0.f, 0.f};

  const short* pa0 = A + (size_t)(r0 + lm) * K + lq * 8;
  const short* pa1 = A + (size_t)(r0 + 16 + lm) * K + lq * 8;

  s16x8 af0 = *(const s16x8*)pa0, af1 = *(const s16x8*)pa1;
  for (int k0 = 0; k0 < K; k0 += 32) {
    s16x8 nf0, nf1;
    if (k0 + 32 < K) {
      nf0 = *(const s16x8*)(pa0 + k0 + 32);
      nf1 = *(const s16x8*)(pa1 + k0 + 32);
    }
    const short* pb = Bt + (size_t)lm * K + k0 + lq * 8;
#pragma unroll
    for (int ni = 0; ni < 4; ni++) {
      s16x8 b = *(const s16x8*)(pb + (size_t)ni * 16 * K);
      acc[0][ni] = __builtin_amdgcn_mfma_f32_16x16x32_bf16(af0, b, acc[0][ni], 0, 0, 0);
      acc[1][ni] = __builtin_amdgcn_mfma_f32_16x16x32_bf16(af1, b, acc[1][ni], 0, 0, 0);
    }
    af0 = nf0;
    af1 = nf1;
  }

#pragma unroll
  for (int mi = 0; mi < 2; mi++)
#pragma unroll
    for (int r = 0; r < 4; r++) {
      int row = r0 + mi * 16 + lq * 4 + r;
      float di = dinv[row];
      float mx = 0.f;
#pragma unroll
      for (int ni = 0; ni < 4; ni++) mx = fmaxf(mx, fabsf(acc[mi][ni][r]));
      mx *= di;
#pragma unroll
      for (int w = 1; w < 16; w <<= 1) mx = fmaxf(mx, __shfl_xor(mx, w));
      float inv = 127.0f / fmaxf(mx, 1e-30f);
#pragma unroll
      for (int ni = 0; ni < 4; ni++) {
        int qv = (int)rintf(acc[mi][ni][r] * di * inv) + 128;
        q[(size_t)row * N + ni * 16 + lm] = (unsigned char)qv;
      }
      if (lm == 0) qscale[row] = mx * (1.0f / 127.0f);
    }
}

// ---------------- aggregation (CSR, no atomics, int8 gathers) --------------
// a[j] = sum_e s_e*u_e[j] - 128*sum_e s_e  (bias folded; rows carry dinv[src]
// from the GEMM epilogue). dst-side di applied once at the end.
// layer 1: 256 dims q8 = 256B row. Half-wave = 32 lanes x uint2 (8B/lane);
// halves walk even/odd edges; 4-deep unroll (proven structure, no spill).
__global__ __launch_bounds__(256) void agg1_kernel(
    const unsigned char* __restrict__ q1, const float* __restrict__ qs,
    const float* __restrict__ dinv,
    const unsigned* __restrict__ row_start, const unsigned* __restrict__ row_cnt,
    const int* __restrict__ csr_src, short* __restrict__ out, int n) {
  int node = blockIdx.x * 4 + (threadIdx.x >> 6);
  if (node >= n) return;
  const int lane = threadIdx.x & 63;
  const int half = lane >> 5;
  const int d0 = (lane & 31) * 8;  // 8 dims per lane
  float a[8];
#pragma unroll
  for (int j = 0; j < 8; j++) a[j] = 0.f;
  float K = 0.f;
  if (half == 0) {  // self loop
    uint2 v = *(const uint2*)(q1 + (size_t)node * HID + d0);
    float w = qs[node];
    K += w;
#pragma unroll
    for (int j = 0; j < 4; j++) {
      a[j] += ub(v.x, j) * w;
      a[j + 4] += ub(v.y, j) * w;
    }
  }
  unsigned e = row_start[node] + half;
  const unsigned e1 = row_start[node] + row_cnt[node];
  for (; e + 6 < e1; e += 8) {
    int s0 = csr_src[e], s1 = csr_src[e + 2];
    int s2 = csr_src[e + 4], s3 = csr_src[e + 6];
    float w0 = qs[s0], w1 = qs[s1], w2 = qs[s2], w3 = qs[s3];
    uint2 v0 = *(const uint2*)(q1 + (size_t)s0 * HID + d0);
    uint2 v1 = *(const uint2*)(q1 + (size_t)s1 * HID + d0);
    uint2 v2 = *(const uint2*)(q1 + (size_t)s2 * HID + d0);
    uint2 v3 = *(const uint2*)(q1 + (size_t)s3 * HID + d0);
    K += (w0 + w1) + (w2 + w3);
#pragma unroll
    for (int j = 0; j < 4; j++) {
      a[j] += ub(v0.x, j) * w0 + ub(v1.x, j) * w1 + ub(v2.x, j) * w2 +
              ub(v3.x, j) * w3;
      a[j + 4] += ub(v0.y, j) * w0 + ub(v1.y, j) * w1 + ub(v2.y, j) * w2 +
                  ub(v3.y, j) * w3;
    }
  }
  for (; e < e1; e += 2) {
    int s0 = csr_src[e];
    float w0 = qs[s0];
    uint2 v0 = *(const uint2*)(q1 + (size_t)s0 * HID + d0);
    K += w0;
#pragma unroll
    for (int j = 0; j < 4; j++) {
      a[j] += ub(v0.x, j) * w0;
      a[j + 4] += ub(v0.y, j) * w0;
    }
  }
#pragma unroll
  for (int j = 0; j < 8; j++) a[j] += __shfl_xor(a[j], 32);
  K += __shfl_xor(K, 32);
  if (half == 0) {
    const float di = dinv[node];
    const float bias = 128.0f * K;
    s16x8 o;
#pragma unroll
    for (int j = 0; j < 8; j++)
      o[j] = (short)f2bf(fmaxf((a[j] - bias) * di, 0.f));
    *(s16x8*)(out + (size_t)node * HID + d0) = o;
  }
}

// layer 2: 64 dims q8 = 64B row. Quarter-wave = 16 lanes x uint (4B/lane);
// 4 quarters walk edge strides of 4; 4-deep unroll. fp32 out.
__global__ __launch_bounds__(256) void agg2_kernel(
    const unsigned char* __restrict__ q2, const float* __restrict__ qs,
    const float* __restrict__ dinv,
    const unsigned* __restrict__ row_start, const unsigned* __restrict__ row_cnt,
    const int* __restrict__ csr_src, float* __restrict__ out, int n) {
  int node = blockIdx.x * 4 + (threadIdx.x >> 6);
  if (node >= n) return;
  const int lane = threadIdx.x & 63;
  const int q = lane >> 4;
  const int d0 = (lane & 15) * 4;  // 4 dims per lane
  float a[4] = {0.f, 0.f, 0.f, 0.f};
  float K = 0.f;
  if (q == 0) {  // self loop
    unsigned v = *(const unsigned*)(q2 + (size_t)node * OUTD + d0);
    float w = qs[node];
    K += w;
#pragma unroll
    for (int j = 0; j < 4; j++) a[j] += ub(v, j) * w;
  }
  unsigned e = row_start[node] + q;
  const unsigned e1 = row_start[node] + row_cnt[node];
  for (; e + 12 < e1; e += 16) {
    int s0 = csr_src[e], s1 = csr_src[e + 4];
    int s2 = csr_src[e + 8], s3 = csr_src[e + 12];
    float w0 = qs[s0], w1 = qs[s1], w2 = qs[s2], w3 = qs[s3];
    unsigned v0 = *(const unsigned*)(q2 + (size_t)s0 * OUTD + d0);
    unsigned v1 = *(const unsigned*)(q2 + (size_t)s1 * OUTD + d0);
    unsigned v2 = *(const unsigned*)(q2 + (size_t)s2 * OUTD + d0);
    unsigned v3 = *(const unsigned*)(q2 + (size_t)s3 * OUTD + d0);
    K += (w0 + w1) + (w2 + w3);
#pragma unroll
    for (int j = 0; j < 4; j++)
      a[j] += (ub(v0, j) * w0 + ub(v1, j) * w1) +
              (ub(v2, j) * w2 + ub(v3, j) * w3);
  }
  for (; e < e1; e += 4) {
    int s0 = csr_src[e];
    float w0 = qs[s0];
    unsigned v0 = *(const unsigned*)(q2 + (size_t)s0 * OUTD + d0);
    K += w0;
#pragma unroll
    for (int j = 0; j < 4; j++) a[j] += ub(v0, j) * w0;
  }
#pragma unroll
  for (int j = 0; j < 4; j++) {
    a[j] += __shfl_xor(a[j], 16);
    a[j] += __shfl_xor(a[j], 32);
  }
  K += __shfl_xor(K, 16);
  K += __shfl_xor(K, 32);
  if (q == 0) {
    const float di = dinv[node];
    const float bias = 128.0f * K;
    float4 o = make_float4((a[0] - bias) * di, (a[1] - bias) * di,
                           (a[2] - bias) * di, (a[3] - bias) * di);
    *(float4*)(out + (size_t)node * OUTD + d0) = o;
  }
}

// ---------------- launch ----------------

extern "C" void kernel_launch(void* const* d_in, const int* in_sizes, int n_in,
                              void* d_out, int out_size, void* d_ws,
                              size_t ws_size, hipStream_t stream) {
  const float* x = (const float*)d_in[0];
  const float* W1 = (const float*)d_in[1];
  const float* W2 = (const float*)d_in[2];
  const int* ei = (const int*)d_in[3];
  const int E = in_sizes[3] / 2;
  const int Nn = in_sizes[0] / IN_DIM;
  const int* src = ei;
  const int* dst = ei + E;
  const int NB = (Nn + 255) >> BKT_SHIFT;  // 391 (<= MAX_NB)

  char* p = (char*)d_ws;
  auto alloc = [&](size_t bytes) {
    char* r = p;
    p += (bytes + 255) & ~(size_t)255;
    return r;
  };
  unsigned* bucket_cursor = (unsigned*)alloc(512 * 4);
  unsigned* row_start = (unsigned*)alloc((size_t)Nn * 4);
  unsigned* row_cnt = (unsigned*)alloc((size_t)Nn * 4);
  float* dinv = (float*)alloc((size_t)Nn * 4);
  float* qs1 = (float*)alloc((size_t)Nn * 4);
  float* qs2 = (float*)alloc((size_t)Nn * 4);
  int* csr_src = (int*)alloc((size_t)MAX_NB * SEG_CAP * 4);  // 26.2MB
  unsigned* entry_buf = (unsigned*)alloc((size_t)MAX_NB * SEG_CAP * 4);
  short* Wt1 = (short*)alloc((size_t)IN_DIM * HID * 2);
  short* Wt2 = (short*)alloc((size_t)HID * OUTD * 2);
  short* agg1 = (short*)alloc((size_t)Nn * HID * 2);
  // entry_buf (26.2MB) is dead after build; reuse it (lifetimes are serial):
  //   q1 [0, 25.6MB)    written by gemm1 (after build), read by agg1
  //   q2 [16MB, 22.4MB) written by gemm2 (after agg1, q1 dead), read by agg2
  unsigned char* q1 = (unsigned char*)entry_buf;
  unsigned char* q2 = (unsigned char*)entry_buf + (16u << 20);

  pack_init_kernel<<<(IN_DIM * HID + 255) / 256, 256, 0, stream>>>(
      W1, W2, Wt1, Wt2, bucket_cursor);
  scatter_kernel<<<(E + EDGES_PER_BLOCK - 1) / EDGES_PER_BLOCK, 256, 0,
                   stream>>>(src, dst, E, bucket_cursor, entry_buf);
  build_kernel<<<NB, 512, 0, stream>>>(entry_buf, bucket_cursor, Nn, csr_src,
                                       row_start, row_cnt, dinv);
  gemm1_kernel<<<(Nn / 32 + 3) / 4, 256, 0, stream>>>(x, Wt1, q1, qs1, dinv,
                                                      Nn);
  agg1_kernel<<<(Nn + 3) / 4, 256, 0, stream>>>(q1, qs1, dinv, row_start,
                                                row_cnt, csr_src, agg1, Nn);
  gemm2_kernel<<<(Nn / 32 + 3) / 4, 256, 0, stream>>>(agg1, Wt2, q2, qs2,
                                                      dinv, Nn);
  agg2_kernel<<<(Nn + 3) / 4, 256, 0, stream>>>(q2, qs2, dinv, row_start,
                                                row_cnt, csr_src,
                                                (float*)d_out, Nn);
}

// Round 5
// 609.844 us; speedup vs baseline: 1.3255x; 1.3255x over previous
//
#include <hip/hip_runtime.h>

// ---------------------------------------------------------------------------
// GCN 2-layer forward on MI355X.
// R10: R9's no-LDS GEMM was latency-bound (occ 9%, 16 dependent L2 loads per
// K-step, 308us). Revert GEMMs to R8's proven LDS forms + T14 issue-early/
// write-late staging split: per K-step {write regs->LDS; ISSUE next loads;
// barrier; ds_read+MFMA; barrier} so global latency hides under MFMA phase.
// Keep R9's scatter (EPB 2048) + build (512thr) -- measured net-neutral.
// Pipeline: packW+init -> scatter -> build -> GEMM1(*dinv,->q8) ->
//           agg1(+relu,bf16) -> GEMM2(*dinv,->q8) -> agg2 -> d_out(fp32)
// ---------------------------------------------------------------------------

typedef short s16x8 __attribute__((ext_vector_type(8)));   // 8 bf16 = 4 VGPRs
typedef float f32x4 __attribute__((ext_vector_type(4)));

static constexpr int IN_DIM = 512;
static constexpr int HID = 256;
static constexpr int OUTD = 64;

static constexpr int BKT_SHIFT = 8;           // 256 nodes / bucket
static constexpr int MAX_NB = 400;            // >= ceil(100000/256)=391
static constexpr int CAP_BIN = 16;            // scatter LDS bin depth
static constexpr int EDGES_PER_BLOCK = 2048;  // scatter chunk (mean bin 5.2)
static constexpr int SEG_CAP = 16384;         // bucket segment (mean 8192 +90s)

static __device__ __forceinline__ float bf2f(unsigned short u) {
  unsigned int x = ((unsigned int)u) << 16;
  float f;
  __builtin_memcpy(&f, &x, 4);
  return f;
}
static __device__ __forceinline__ unsigned short f2bf(float f) {
  unsigned int x;
  __builtin_memcpy(&x, &f, 4);
  unsigned int r = x + 0x7fffu + ((x >> 16) & 1u);  // RNE
  return (unsigned short)(r >> 16);
}
// byte k of x as float (LLVM folds to v_cvt_f32_ubyteN)
static __device__ __forceinline__ float ub(unsigned int x, int k) {
  return (float)((x >> (8 * k)) & 0xffu);
}

// ---------------- fused: pack W1/W2 to bf16 [N,K] + init bucket cursors -----
__global__ __launch_bounds__(256) void pack_init_kernel(
    const float* __restrict__ W1, const float* __restrict__ W2,
    short* __restrict__ Wt1, short* __restrict__ Wt2,
    unsigned* __restrict__ bucket_cursor) {
  int idx = blockIdx.x * blockDim.x + threadIdx.x;
  if (idx < IN_DIM * HID) {  // Wt1[n*K+k] = W1[k*N+n]
    int n = idx / IN_DIM, k = idx - n * IN_DIM;
    Wt1[idx] = (short)f2bf(W1[(size_t)k * HID + n]);
  }
  if (idx < HID * OUTD) {
    int n = idx / HID, k = idx - n * HID;
    Wt2[idx] = (short)f2bf(W2[(size_t)k * OUTD + n]);
  }
  if (idx < 512) bucket_cursor[idx] = (unsigned)idx * SEG_CAP;
}

// bin edges by dst-bucket into fixed segments; entry = (src<<8)|(dst&255)
__global__ __launch_bounds__(256) void scatter_kernel(
    const int* __restrict__ src, const int* __restrict__ dst, int E,
    unsigned* __restrict__ bucket_cursor, unsigned* __restrict__ entry_buf) {
  __shared__ unsigned cnt[MAX_NB];
  __shared__ unsigned poss[MAX_NB];
  __shared__ unsigned buf[MAX_NB * CAP_BIN];
  const int tid = threadIdx.x;
  const int e0 = blockIdx.x * EDGES_PER_BLOCK;
  const int e1 = min(E, e0 + EDGES_PER_BLOCK);
  for (int i = tid; i < MAX_NB; i += 256) cnt[i] = 0;
  __syncthreads();
  for (int e = e0 + tid; e < e1; e += 256) {
    int d = dst[e];
    unsigned entry = (((unsigned)src[e]) << 8) | ((unsigned)d & 255u);
    int bkt = d >> BKT_SHIFT;
    unsigned slot = atomicAdd(&cnt[bkt], 1u);
    if (slot < CAP_BIN) {
      buf[bkt * CAP_BIN + slot] = entry;
    } else {  // rare overflow: direct scattered write
      unsigned pos = atomicAdd(&bucket_cursor[bkt], 1u);
      entry_buf[pos] = entry;
    }
  }
  __syncthreads();
  for (int b = tid; b < MAX_NB; b += 256) {
    unsigned c = min(cnt[b], (unsigned)CAP_BIN);
    poss[b] = c ? atomicAdd(&bucket_cursor[b], c) : 0u;
  }
  __syncthreads();
  for (int b0 = 0; b0 < MAX_NB; b0 += 16) {
    int b = b0 + (tid >> 4);
    int i = tid & 15;
    unsigned c = min(cnt[b], (unsigned)CAP_BIN);
    if ((unsigned)i < c) entry_buf[poss[b] + i] = buf[b * CAP_BIN + i];
  }
}

// one block per bucket: LDS counting sort -> csr in bucket segment; emits
// dinv, row_start, row_cnt. 512 threads (edge loops); scan confined to <256.
__global__ __launch_bounds__(512) void build_kernel(
    const unsigned* __restrict__ entry_buf,
    const unsigned* __restrict__ bucket_cursor, int Nn,
    int* __restrict__ csr_src, unsigned* __restrict__ row_start,
    unsigned* __restrict__ row_cnt, float* __restrict__ dinv) {
  __shared__ unsigned hist[256];
  __shared__ unsigned scn[256];
  const int tid = threadIdx.x;
  const int b = blockIdx.x;
  const unsigned nb0 = (unsigned)b * SEG_CAP;
  const int n_e = (int)(bucket_cursor[b] - nb0);

  if (tid < 256) hist[tid] = 0;
  __syncthreads();
  for (int i = tid; i < n_e; i += 512)
    atomicAdd(&hist[entry_buf[nb0 + i] & 255u], 1u);
  __syncthreads();

  unsigned v = (tid < 256) ? hist[tid] : 0u;
  if (tid < 256) scn[tid] = v;
  __syncthreads();
  for (int off = 1; off < 256; off <<= 1) {
    unsigned t = (tid < 256 && tid >= off) ? scn[tid - off] : 0u;
    __syncthreads();
    if (tid < 256) scn[tid] += t;
    __syncthreads();
  }
  unsigned excl = 0;
  if (tid < 256) {
    excl = scn[tid] - v;
    int node = (b << BKT_SHIFT) + tid;
    if (node < Nn) {
      dinv[node] = rsqrtf((float)v + 1.0f);  // +1 self loop
      row_start[node] = nb0 + excl;
      row_cnt[node] = v;
    }
  }
  __syncthreads();
  if (tid < 256) {
    scn[tid] = excl;
    hist[tid] = 0;  // reuse as per-node rank counters
  }
  __syncthreads();

  for (int i = tid; i < n_e; i += 512) {
    unsigned en = entry_buf[nb0 + i];
    unsigned d = en & 255u;
    unsigned r = atomicAdd(&hist[d], 1u);
    csr_src[nb0 + scn[d] + r] = (int)(en >> 8);
  }
}

// ---------------- GEMM1: q1 = quant8(dinv[row] * (x @ Wt1^T)) ---------------
// 512 threads, BM=128 x BN=256, 8 waves (2M x 4N). T14 depth-1 pipeline:
// {write staged regs->LDS; issue next K-step loads; barrier; MFMA; barrier}.
__global__ __launch_bounds__(512) void gemm1_kernel(
    const float* __restrict__ A, const short* __restrict__ Bt,
    unsigned char* __restrict__ q, float* __restrict__ qscale,
    const float* __restrict__ dinv, int M) {
  constexpr int K = IN_DIM;  // 512
  constexpr int BN = HID;    // 256
  constexpr int BM = 128, BK = 32;
  __shared__ short sA[BM * BK];  // 8 KB
  __shared__ short sB[BN * BK];  // 16 KB
  __shared__ int rmax[BM];
  const int tid = threadIdx.x;
  const int wave = tid >> 6, lane = tid & 63;
  const int lm = lane & 15, lq = lane >> 4;
  const int row0 = blockIdx.x * BM;
  const int wm0 = (wave >> 2) * 64;  // 0 / 64
  const int wn0 = (wave & 3) * 64;   // 0..192

  f32x4 acc[4][4];
#pragma unroll
  for (int i = 0; i < 4; i++)
#pragma unroll
    for (int j = 0; j < 4; j++) acc[i][j] = f32x4{0.f, 0.f, 0.f, 0.f};

  // staging geometry (fixed per thread)
  const int am = tid >> 2, akc = tid & 3;  // A: 128 rows x 4 chunks of 8
  const int arow = row0 + am;
  const float* pa = A + (size_t)arow * K + akc * 8;  // guarded by arow<M
  const int bn0 = tid >> 2, bkc0 = (tid & 3);        // B seg 0: rows 0..127
  const int bn1 = (tid + 512) >> 2, bkc1 = (tid & 3);// B seg 1: rows 128..255
  const short* pb0 = Bt + (size_t)bn0 * K + bkc0 * 8;
  const short* pb1 = Bt + (size_t)bn1 * K + bkc1 * 8;

  // prologue: load k0 = 0 into regs
  float4 fa0 = make_float4(0, 0, 0, 0), fa1 = fa0;
  if (arow < M) {
    fa0 = *(const float4*)(pa + 0);
    fa1 = *(const float4*)(pa + 4);
  }
  s16x8 vb0 = *(const s16x8*)(pb0 + 0);
  s16x8 vb1 = *(const s16x8*)(pb1 + 0);

  for (int k0 = 0; k0 < K; k0 += BK) {
    // (1) write staged regs -> LDS (vmcnt wait folds here)
    {
      s16x8 v;
      v[0] = (short)f2bf(fa0.x); v[1] = (short)f2bf(fa0.y);
      v[2] = (short)f2bf(fa0.z); v[3] = (short)f2bf(fa0.w);
      v[4] = (short)f2bf(fa1.x); v[5] = (short)f2bf(fa1.y);
      v[6] = (short)f2bf(fa1.z); v[7] = (short)f2bf(fa1.w);
      *(s16x8*)&sA[am * BK + akc * 8] = v;
      *(s16x8*)&sB[bn0 * BK + bkc0 * 8] = vb0;
      *(s16x8*)&sB[bn1 * BK + bkc1 * 8] = vb1;
    }
    // (2) issue next K-step loads; they land during the MFMA phase
    if (k0 + BK < K) {
      if (arow < M) {
        fa0 = *(const float4*)(pa + k0 + BK);
        fa1 = *(const float4*)(pa + k0 + BK + 4);
      }
      vb0 = *(const s16x8*)(pb0 + k0 + BK);
      vb1 = *(const s16x8*)(pb1 + k0 + BK);
    }
    __syncthreads();

    s16x8 af[4], bfr[4];
#pragma unroll
    for (int mi = 0; mi < 4; mi++)
      af[mi] = *(const s16x8*)&sA[(wm0 + mi * 16 + lm) * BK + lq * 8];
#pragma unroll
    for (int ni = 0; ni < 4; ni++)
      bfr[ni] = *(const s16x8*)&sB[(wn0 + ni * 16 + lm) * BK + lq * 8];
#pragma unroll
    for (int mi = 0; mi < 4; mi++)
#pragma unroll
      for (int ni = 0; ni < 4; ni++)
        acc[mi][ni] = __builtin_amdgcn_mfma_f32_16x16x32_bf16(
            af[mi], bfr[ni], acc[mi][ni], 0, 0, 0);
    __syncthreads();
  }

  // ---- epilogue: rowmax (over all 256 cols) then u8 quant ----
  for (int i = tid; i < BM; i += 512) rmax[i] = 0;
  __syncthreads();
  // C/D layout (m89-verified): col = lane&15, row = (lane>>4)*4 + reg
#pragma unroll
  for (int mi = 0; mi < 4; mi++)
#pragma unroll
    for (int r = 0; r < 4; r++) {
      int lrow = wm0 + mi * 16 + lq * 4 + r;
      int row = row0 + lrow;
      float di = (row < M) ? dinv[row] : 0.f;
      float mx = 0.f;
#pragma unroll
      for (int ni = 0; ni < 4; ni++) mx = fmaxf(mx, fabsf(acc[mi][ni][r]));
      mx *= di;  // di >= 0
#pragma unroll
      for (int w = 1; w < 16; w <<= 1) mx = fmaxf(mx, __shfl_xor(mx, w));
      if (lm == 0) atomicMax(&rmax[lrow], __float_as_int(mx));
    }
  __syncthreads();
#pragma unroll
  for (int mi = 0; mi < 4; mi++)
#pragma unroll
    for (int r = 0; r < 4; r++) {
      int lrow = wm0 + mi * 16 + lq * 4 + r;
      int row = row0 + lrow;
      if (row >= M) continue;
      float di = dinv[row];
      float rm = __int_as_float(rmax[lrow]);
      float inv = 127.0f / fmaxf(rm, 1e-30f);
#pragma unroll
      for (int ni = 0; ni < 4; ni++) {
        int col = wn0 + ni * 16 + lm;
        int qv = (int)rintf(acc[mi][ni][r] * di * inv) + 128;
        q[(size_t)row * BN + col] = (unsigned char)qv;
      }
      if (wn0 == 0 && lm == 0) qscale[row] = rm * (1.0f / 127.0f);
    }
}

// ---------------- GEMM2: q2 = quant8(dinv[row] * (agg1 @ Wt2^T)) ------------
// 256 threads, BM=256 x BN=64, 4 waves row-split; wave-local rowmax.
// Same T14 depth-1 staging pipeline.
__global__ __launch_bounds__(256) void gemm2_kernel(
    const short* __restrict__ A, const short* __restrict__ Bt,
    unsigned char* __restrict__ q, float* __restrict__ qscale,
    const float* __restrict__ dinv, int M) {
  constexpr int K = HID;   // 256
  constexpr int BN = OUTD; // 64
  constexpr int BM = 256, BK = 32;
  __shared__ short sA[BM * BK];  // 16 KB
  __shared__ short sB[BN * BK];  // 4 KB
  const int tid = threadIdx.x;
  const int wave = tid >> 6, lane = tid & 63;
  const int lm = lane & 15, lq = lane >> 4;
  const int row0 = blockIdx.x * BM;
  const int wm0 = wave * 64;

  f32x4 acc[4][4];
#pragma unroll
  for (int i = 0; i < 4; i++)
#pragma unroll
    for (int j = 0; j < 4; j++) acc[i][j] = f32x4{0.f, 0.f, 0.f, 0.f};

  // staging geometry: A 4 segs x (64 rows x 4 chunks), B 1 seg
  int amr[4];
  const short* par[4];
#pragma unroll
  for (int i = 0; i < 4; i++) {
    int idx = tid + i * 256;
    amr[i] = idx >> 2;
    par[i] = A + (size_t)(row0 + amr[i]) * K + (idx & 3) * 8;
  }
  const int bn = tid >> 2, bkc = tid & 3;
  const short* pb = Bt + (size_t)bn * K + bkc * 8;

  s16x8 va[4], vb;
#pragma unroll
  for (int i = 0; i < 4; i++) {
    va[i] = s16x8{0, 0, 0, 0, 0, 0, 0, 0};
    if (row0 + amr[i] < M) va[i] = *(const s16x8*)(par[i] + 0);
  }
  vb = *(const s16x8*)(pb + 0);

  for (int k0 = 0; k0 < K; k0 += BK) {
#pragma unroll
    for (int i = 0; i < 4; i++) {
      int idx = tid + i * 256;
      *(s16x8*)&sA[(idx >> 2) * BK + (idx & 3) * 8] = va[i];
    }
    *(s16x8*)&sB[bn * BK + bkc * 8] = vb;
    if (k0 + BK < K) {
#pragma unroll
      for (int i = 0; i < 4; i++) {
        if (row0 + amr[i] < M) va[i] = *(const s16x8*)(par[i] + k0 + BK);
      }
      vb = *(const s16x8*)(pb + k0 + BK);
    }
    __syncthreads();

    s16x8 af[4], bfr[4];
#pragma unroll
    for (int mi = 0; mi < 4; mi++)
      af[mi] = *(const s16x8*)&sA[(wm0 + mi * 16 + lm) * BK + lq * 8];
#pragma unroll
    for (int ni = 0; ni < 4; ni++)
      bfr[ni] = *(const s16x8*)&sB[(ni * 16 + lm) * BK + lq * 8];
#pragma unroll
    for (int mi = 0; mi < 4; mi++)
#pragma unroll
      for (int ni = 0; ni < 4; ni++)
        acc[mi][ni] = __builtin_amdgcn_mfma_f32_16x16x32_bf16(
            af[mi], bfr[ni], acc[mi][ni], 0, 0, 0);
    __syncthreads();
  }

  // ---- epilogue: wave-local rowmax + u8 quant ----
#pragma unroll
  for (int mi = 0; mi < 4; mi++)
#pragma unroll
    for (int r = 0; r < 4; r++) {
      int row = row0 + wm0 + mi * 16 + lq * 4 + r;
      if (row >= M) continue;
      float di = dinv[row];
      float mx = 0.f;
#pragma unroll
      for (int ni = 0; ni < 4; ni++) mx = fmaxf(mx, fabsf(acc[mi][ni][r]));
      mx *= di;
#pragma unroll
      for (int w = 1; w < 16; w <<= 1) mx = fmaxf(mx, __shfl_xor(mx, w));
      float inv = 127.0f / fmaxf(mx, 1e-30f);
#pragma unroll
      for (int ni = 0; ni < 4; ni++) {
        int col = ni * 16 + lm;
        int qv = (int)rintf(acc[mi][ni][r] * di * inv) + 128;
        q[(size_t)row * BN + col] = (unsigned char)qv;
      }
      if (lm == 0) qscale[row] = mx * (1.0f / 127.0f);
    }
}

// ---------------- aggregation (CSR, no atomics, int8 gathers) --------------
// a[j] = sum_e s_e*u_e[j] - 128*sum_e s_e  (bias folded; rows carry dinv[src]
// from the GEMM epilogue). dst-side di applied once at the end.
// layer 1: 256 dims q8 = 256B row. Half-wave = 32 lanes x uint2 (8B/lane);
// halves walk even/odd edges; 4-deep unroll (proven structure, no spill).
__global__ __launch_bounds__(256) void agg1_kernel(
    const unsigned char* __restrict__ q1, const float* __restrict__ qs,
    const float* __restrict__ dinv,
    const unsigned* __restrict__ row_start, const unsigned* __restrict__ row_cnt,
    const int* __restrict__ csr_src, short* __restrict__ out, int n) {
  int node = blockIdx.x * 4 + (threadIdx.x >> 6);
  if (node >= n) return;
  const int lane = threadIdx.x & 63;
  const int half = lane >> 5;
  const int d0 = (lane & 31) * 8;  // 8 dims per lane
  float a[8];
#pragma unroll
  for (int j = 0; j < 8; j++) a[j] = 0.f;
  float K = 0.f;
  if (half == 0) {  // self loop
    uint2 v = *(const uint2*)(q1 + (size_t)node * HID + d0);
    float w = qs[node];
    K += w;
#pragma unroll
    for (int j = 0; j < 4; j++) {
      a[j] += ub(v.x, j) * w;
      a[j + 4] += ub(v.y, j) * w;
    }
  }
  unsigned e = row_start[node] + half;
  const unsigned e1 = row_start[node] + row_cnt[node];
  for (; e + 6 < e1; e += 8) {
    int s0 = csr_src[e], s1 = csr_src[e + 2];
    int s2 = csr_src[e + 4], s3 = csr_src[e + 6];
    float w0 = qs[s0], w1 = qs[s1], w2 = qs[s2], w3 = qs[s3];
    uint2 v0 = *(const uint2*)(q1 + (size_t)s0 * HID + d0);
    uint2 v1 = *(const uint2*)(q1 + (size_t)s1 * HID + d0);
    uint2 v2 = *(const uint2*)(q1 + (size_t)s2 * HID + d0);
    uint2 v3 = *(const uint2*)(q1 + (size_t)s3 * HID + d0);
    K += (w0 + w1) + (w2 + w3);
#pragma unroll
    for (int j = 0; j < 4; j++) {
      a[j] += ub(v0.x, j) * w0 + ub(v1.x, j) * w1 + ub(v2.x, j) * w2 +
              ub(v3.x, j) * w3;
      a[j + 4] += ub(v0.y, j) * w0 + ub(v1.y, j) * w1 + ub(v2.y, j) * w2 +
                  ub(v3.y, j) * w3;
    }
  }
  for (; e < e1; e += 2) {
    int s0 = csr_src[e];
    float w0 = qs[s0];
    uint2 v0 = *(const uint2*)(q1 + (size_t)s0 * HID + d0);
    K += w0;
#pragma unroll
    for (int j = 0; j < 4; j++) {
      a[j] += ub(v0.x, j) * w0;
      a[j + 4] += ub(v0.y, j) * w0;
    }
  }
#pragma unroll
  for (int j = 0; j < 8; j++) a[j] += __shfl_xor(a[j], 32);
  K += __shfl_xor(K, 32);
  if (half == 0) {
    const float di = dinv[node];
    const float bias = 128.0f * K;
    s16x8 o;
#pragma unroll
    for (int j = 0; j < 8; j++)
      o[j] = (short)f2bf(fmaxf((a[j] - bias) * di, 0.f));
    *(s16x8*)(out + (size_t)node * HID + d0) = o;
  }
}

// layer 2: 64 dims q8 = 64B row. Quarter-wave = 16 lanes x uint (4B/lane);
// 4 quarters walk edge strides of 4; 4-deep unroll. fp32 out.
__global__ __launch_bounds__(256) void agg2_kernel(
    const unsigned char* __restrict__ q2, const float* __restrict__ qs,
    const float* __restrict__ dinv,
    const unsigned* __restrict__ row_start, const unsigned* __restrict__ row_cnt,
    const int* __restrict__ csr_src, float* __restrict__ out, int n) {
  int node = blockIdx.x * 4 + (threadIdx.x >> 6);
  if (node >= n) return;
  const int lane = threadIdx.x & 63;
  const int q = lane >> 4;
  const int d0 = (lane & 15) * 4;  // 4 dims per lane
  float a[4] = {0.f, 0.f, 0.f, 0.f};
  float K = 0.f;
  if (q == 0) {  // self loop
    unsigned v = *(const unsigned*)(q2 + (size_t)node * OUTD + d0);
    float w = qs[node];
    K += w;
#pragma unroll
    for (int j = 0; j < 4; j++) a[j] += ub(v, j) * w;
  }
  unsigned e = row_start[node] + q;
  const unsigned e1 = row_start[node] + row_cnt[node];
  for (; e + 12 < e1; e += 16) {
    int s0 = csr_src[e], s1 = csr_src[e + 4];
    int s2 = csr_src[e + 8], s3 = csr_src[e + 12];
    float w0 = qs[s0], w1 = qs[s1], w2 = qs[s2], w3 = qs[s3];
    unsigned v0 = *(const unsigned*)(q2 + (size_t)s0 * OUTD + d0);
    unsigned v1 = *(const unsigned*)(q2 + (size_t)s1 * OUTD + d0);
    unsigned v2 = *(const unsigned*)(q2 + (size_t)s2 * OUTD + d0);
    unsigned v3 = *(const unsigned*)(q2 + (size_t)s3 * OUTD + d0);
    K += (w0 + w1) + (w2 + w3);
#pragma unroll
    for (int j = 0; j < 4; j++)
      a[j] += (ub(v0, j) * w0 + ub(v1, j) * w1) +
              (ub(v2, j) * w2 + ub(v3, j) * w3);
  }
  for (; e < e1; e += 4) {
    int s0 = csr_src[e];
    float w0 = qs[s0];
    unsigned v0 = *(const unsigned*)(q2 + (size_t)s0 * OUTD + d0);
    K += w0;
#pragma unroll
    for (int j = 0; j < 4; j++) a[j] += ub(v0, j) * w0;
  }
#pragma unroll
  for (int j = 0; j < 4; j++) {
    a[j] += __shfl_xor(a[j], 16);
    a[j] += __shfl_xor(a[j], 32);
  }
  K += __shfl_xor(K, 16);
  K += __shfl_xor(K, 32);
  if (q == 0) {
    const float di = dinv[node];
    const float bias = 128.0f * K;
    float4 o = make_float4((a[0] - bias) * di, (a[1] - bias) * di,
                           (a[2] - bias) * di, (a[3] - bias) * di);
    *(float4*)(out + (size_t)node * OUTD + d0) = o;
  }
}

// ---------------- launch ----------------

extern "C" void kernel_launch(void* const* d_in, const int* in_sizes, int n_in,
                              void* d_out, int out_size, void* d_ws,
                              size_t ws_size, hipStream_t stream) {
  const float* x = (const float*)d_in[0];
  const float* W1 = (const float*)d_in[1];
  const float* W2 = (const float*)d_in[2];
  const int* ei = (const int*)d_in[3];
  const int E = in_sizes[3] / 2;
  const int Nn = in_sizes[0] / IN_DIM;
  const int* src = ei;
  const int* dst = ei + E;
  const int NB = (Nn + 255) >> BKT_SHIFT;  // 391 (<= MAX_NB)

  char* p = (char*)d_ws;
  auto alloc = [&](size_t bytes) {
    char* r = p;
    p += (bytes + 255) & ~(size_t)255;
    return r;
  };
  unsigned* bucket_cursor = (unsigned*)alloc(512 * 4);
  unsigned* row_start = (unsigned*)alloc((size_t)Nn * 4);
  unsigned* row_cnt = (unsigned*)alloc((size_t)Nn * 4);
  float* dinv = (float*)alloc((size_t)Nn * 4);
  float* qs1 = (float*)alloc((size_t)Nn * 4);
  float* qs2 = (float*)alloc((size_t)Nn * 4);
  int* csr_src = (int*)alloc((size_t)MAX_NB * SEG_CAP * 4);  // 26.2MB
  unsigned* entry_buf = (unsigned*)alloc((size_t)MAX_NB * SEG_CAP * 4);
  short* Wt1 = (short*)alloc((size_t)IN_DIM * HID * 2);
  short* Wt2 = (short*)alloc((size_t)HID * OUTD * 2);
  short* agg1 = (short*)alloc((size_t)Nn * HID * 2);
  // entry_buf (26.2MB) is dead after build; reuse it (lifetimes are serial):
  //   q1 [0, 25.6MB)    written by gemm1 (after build), read by agg1
  //   q2 [16MB, 22.4MB) written by gemm2 (after agg1, q1 dead), read by agg2
  unsigned char* q1 = (unsigned char*)entry_buf;
  unsigned char* q2 = (unsigned char*)entry_buf + (16u << 20);

  pack_init_kernel<<<(IN_DIM * HID + 255) / 256, 256, 0, stream>>>(
      W1, W2, Wt1, Wt2, bucket_cursor);
  scatter_kernel<<<(E + EDGES_PER_BLOCK - 1) / EDGES_PER_BLOCK, 256, 0,
                   stream>>>(src, dst, E, bucket_cursor, entry_buf);
  build_kernel<<<NB, 512, 0, stream>>>(entry_buf, bucket_cursor, Nn, csr_src,
                                       row_start, row_cnt, dinv);
  gemm1_kernel<<<(Nn + 127) / 128, 512, 0, stream>>>(x, Wt1, q1, qs1, dinv,
                                                     Nn);
  agg1_kernel<<<(Nn + 3) / 4, 256, 0, stream>>>(q1, qs1, dinv, row_start,
                                                row_cnt, csr_src, agg1, Nn);
  gemm2_kernel<<<(Nn + 255) / 256, 256, 0, stream>>>(agg1, Wt2, q2, qs2, dinv,
                                                     Nn);
  agg2_kernel<<<(Nn + 3) / 4, 256, 0, stream>>>(q2, qs2, dinv, row_start,
                                                row_cnt, csr_src,
                                                (float*)d_out, Nn);
}